// Round 17
// baseline (89.026 us; speedup 1.0000x reference)
//
#include <hip/hip_runtime.h>
#include <float.h>
#include <math.h>

typedef __attribute__((ext_vector_type(8))) short short8;
typedef __attribute__((ext_vector_type(4))) float f32x4;

constexpr int SEQL = 2048;
constexpr int NQH  = 16;   // 2*H query/key heads
constexpr int NVH  = 8;    // value heads
constexpr int DHD  = 32;
constexpr float LAMB_INIT = 0.4707130183436648f;   // 0.8 - 0.6*exp(-0.6)
constexpr float REPS      = 1e-8f;
constexpr float QW        = 0.25503492f;           // 32^-0.5 * log2(e) (scores in log2 domain)

static __device__ __forceinline__ unsigned short f2bf(float f) {
    union { float f; unsigned u; } a; a.f = f;
    unsigned u = a.u;
    u += 0x7fffu + ((u >> 16) & 1u);
    return (unsigned short)(u >> 16);
}

static __device__ __forceinline__ unsigned cvtpk(float lo, float hi) {
    unsigned r;
    asm("v_cvt_pk_bf16_f32 %0, %1, %2" : "=v"(r) : "v"(lo), "v"(hi));
    return r;
}

// guaranteed single-instruction 2^x
static __device__ __forceinline__ float expv(float x) {
    float r;
    asm("v_exp_f32 %0, %1" : "=v"(r) : "v"(x));
    return r;
}

static __device__ __forceinline__ void stage16(const unsigned short* g, unsigned short* l) {
    __builtin_amdgcn_global_load_lds(
        (const __attribute__((address_space(1))) unsigned int*)g,
        (__attribute__((address_space(3))) unsigned int*)l, 16, 0, 0);
}

// ============================================================================
// Shared device bodies
// ============================================================================

// ---- qkv unit: project 64 rows x 64 cols using a prepped LDS weight panel ----
static __device__ __forceinline__ void qkv_unit(
        const float* __restrict__ x, const float* __restrict__ Wq,
        const float* __restrict__ Wkv,
        unsigned short* __restrict__ Q, unsigned short* __restrict__ Kf,
        unsigned short* __restrict__ Vf,
        unsigned short* wlds, int by, int bx,
        int t, int w, int lane, int lr, int lg) {
    {   // weight panel prep: 2048 k-quads -> LDS fragment order
        const float* wsrc; int wstride, c0; float wscale;
        if (by < 8)       { wsrc = Wq;  wstride = 512;  c0 = by * 64;          wscale = QW;  }
        else if (by < 16) { wsrc = Wkv; wstride = 1024; c0 = (by - 8) * 64;    wscale = 1.f; }
        else              { wsrc = Wkv; wstride = 1024; c0 = 512 + (by - 16) * 64; wscale = 1.f; }
        #pragma unroll
        for (int i = 0; i < 8; ++i) {
            int q = t + i * 256;       // 0..2047
            int kq = q >> 6, cc = q & 63;
            int k0 = kq * 4;
            const float* p = wsrc + (size_t)k0 * wstride + c0 + cc;
            float v0 = p[0] * wscale;
            float v1 = p[wstride] * wscale;
            float v2 = p[2 * wstride] * wscale;
            float v3 = p[3 * wstride] * wscale;
            int ct2 = cc >> 4, clr = cc & 15, kk = k0 >> 5, klg = (k0 >> 3) & 3, j0 = k0 & 7;
            uint2 pk;
            pk.x = cvtpk(v0, v1); pk.y = cvtpk(v2, v3);
            *(uint2*)(wlds + (size_t)(ct2 * 4 + kk) * 512 + klg * 128 + clr * 8 + j0) = pk;
        }
    }
    // x A-fragments (f32 -> bf16 in-register)
    int r0 = bx * 64 + w * 16;
    short8 ax[4];
    #pragma unroll
    for (int kk = 0; kk < 4; ++kk) {
        const float* xp = x + (size_t)(r0 + lr) * 128 + kk * 32 + lg * 8;
        float4 v0 = *(const float4*)xp;
        float4 v1 = *(const float4*)(xp + 4);
        union { short8 v; unsigned uu[4]; } ua;
        ua.uu[0] = cvtpk(v0.x, v0.y);
        ua.uu[1] = cvtpk(v0.z, v0.w);
        ua.uu[2] = cvtpk(v1.x, v1.y);
        ua.uu[3] = cvtpk(v1.z, v1.w);
        ax[kk] = ua.v;
    }
    __syncthreads();                  // panel ready
    f32x4 acc[4];
    #pragma unroll
    for (int ct2 = 0; ct2 < 4; ++ct2) acc[ct2] = (f32x4){0.f, 0.f, 0.f, 0.f};
    if (by < 16) {
        // swapped: D[i=4lg+r = col-in-16][j=lr = x-row] -> 8B stores
        #pragma unroll
        for (int ct2 = 0; ct2 < 4; ++ct2)
            #pragma unroll
            for (int kk = 0; kk < 4; ++kk) {
                short8 bw = *(const short8*)(wlds + (size_t)(ct2 * 4 + kk) * 512 + lane * 8);
                acc[ct2] = __builtin_amdgcn_mfma_f32_16x16x32_bf16(bw, ax[kk], acc[ct2], 0, 0, 0);
            }
        int gr = r0 + lr;
        int l = gr & 2047, b = gr >> 11;
        if (by < 8) {                  // Q row-major (b,n,l,d)
            #pragma unroll
            for (int ct2 = 0; ct2 < 4; ++ct2) {
                int col = by * 64 + ct2 * 16 + 4 * lg;
                int n = col >> 5, d = col & 31;
                uint2 pk;
                pk.x = cvtpk(acc[ct2][0], acc[ct2][1]);
                pk.y = cvtpk(acc[ct2][2], acc[ct2][3]);
                *(uint2*)(Q + (((size_t)(b * NQH + n)) * SEQL + l) * DHD + d) = pk;
            }
        } else {                       // Kf fragment order
            size_t lpart = (size_t)((l >> 6) * 4 + ((l >> 4) & 3)) * 512 + (l & 15) * 8;
            #pragma unroll
            for (int ct2 = 0; ct2 < 4; ++ct2) {
                int ck = by * 64 + ct2 * 16 + 4 * lg - 512;
                int n = ck >> 5, dk = ck & 31;
                uint2 pk;
                pk.x = cvtpk(acc[ct2][0], acc[ct2][1]);
                pk.y = cvtpk(acc[ct2][2], acc[ct2][3]);
                *(uint2*)(Kf + ((size_t)(b * NQH + n)) * 65536 + lpart
                             + (dk >> 3) * 128 + (dk & 7)) = pk;
            }
        }
    } else {
        // unswapped: D[i=4lg+r = x-row][j=lr = col-in-16]
        #pragma unroll
        for (int ct2 = 0; ct2 < 4; ++ct2)
            #pragma unroll
            for (int kk = 0; kk < 4; ++kk) {
                short8 bw = *(const short8*)(wlds + (size_t)(ct2 * 4 + kk) * 512 + lane * 8);
                acc[ct2] = __builtin_amdgcn_mfma_f32_16x16x32_bf16(ax[kk], bw, acc[ct2], 0, 0, 0);
            }
        int gr0 = r0 + 4 * lg;
        int b = gr0 >> 11, l0 = gr0 & 2047;
        size_t lpart = (size_t)((l0 >> 6) * 2 + ((l0 >> 5) & 1)) * 2048
                     + ((l0 >> 4) & 1) * 4 + ((l0 >> 2) & 3) * 128;   // + u(=r)
        #pragma unroll
        for (int ct2 = 0; ct2 < 4; ++ct2) {
            int cv = by * 64 + 16 * ct2 + lr - 1024;
            int h = cv >> 6, d = cv & 63;
            uint2 pk;
            pk.x = cvtpk(acc[ct2][0], acc[ct2][1]);
            pk.y = cvtpk(acc[ct2][2], acc[ct2][3]);
            *(uint2*)(Vf + ((size_t)(b * NVH + h)) * 131072
                         + (size_t)(d >> 4) * 512 + (d & 15) * 8 + lpart) = pk;
        }
    }
}

// ---- attn body: r5/r11/r12 schedule (best measured), one block = one head-pair
static __device__ __forceinline__ void attn_body(
        const unsigned short* __restrict__ Q, const unsigned short* __restrict__ Kf,
        const unsigned short* __restrict__ Vf, const unsigned long long* __restrict__ bits,
        const float* __restrict__ lq1, const float* __restrict__ lk1,
        const float* __restrict__ lq2, const float* __restrict__ lk2,
        const float* __restrict__ gamma, unsigned short* __restrict__ Ab,
        unsigned short (*lds)[8192], int lid,
        int w, int lane, int lr, int lg) {
    int swz = (lid & 7) * 64 + (lid >> 3);    // XCD-aware, bijective (512 % 8 == 0)
    int qtile = swz & 31, bh = swz >> 5;
    int b = bh >> 3, h = bh & 7;
    int q0 = qtile * 64 + w * 16;
    int bnA = b * NQH + 2 * h;

    short8 aqA = *(const short8*)(Q + (((size_t)bnA) * SEQL + q0 + lr) * DHD + lg * 8);
    short8 aqB = *(const short8*)(Q + (((size_t)(bnA + 1)) * SEQL + q0 + lr) * DHD + lg * 8);
    const unsigned short* KA = Kf + ((size_t)bnA) * 65536;
    const unsigned short* KB = KA + 65536;
    const unsigned short* VB = Vf + ((size_t)(b * NVH + h)) * 131072;
    const unsigned long long* mrow = bits + ((size_t)b * SEQL + q0 + lr) * 32;

    short8 one8;
    #pragma unroll
    for (int i = 0; i < 8; ++i) one8[i] = (short)0x3F80;   // bf16 1.0

    auto stage_tile = [&](int bf, int it) {
        #pragma unroll
        for (int j = 0; j < 4; ++j) {
            int c = 4 * w + j;
            const unsigned short* src =
                (c < 4) ? (KA + (size_t)it * 2048 + c * 512)
              : (c < 8) ? (KB + (size_t)it * 2048 + (c - 4) * 512)
                        : (VB + (size_t)it * 4096 + (c - 8) * 512);
            stage16(src + lane * 8, &lds[bf][c * 512]);
        }
    };

    f32x4 oA[4], oB[4], sumA, sumB;
    #pragma unroll
    for (int m = 0; m < 4; ++m) { oA[m] = (f32x4){0,0,0,0}; oB[m] = (f32x4){0,0,0,0}; }
    sumA = (f32x4){0,0,0,0}; sumB = (f32x4){0,0,0,0};
    unsigned long long mw = mrow[0];

    short8 paE[4], paO[4], bvE[8], bvO[8];
    #pragma unroll
    for (int i = 0; i < 4; ++i) { paE[i] = (short8){0,0,0,0,0,0,0,0}; paO[i] = (short8){0,0,0,0,0,0,0,0}; }
    #pragma unroll
    for (int i = 0; i < 8; ++i) { bvE[i] = (short8){0,0,0,0,0,0,0,0}; bvO[i] = (short8){0,0,0,0,0,0,0,0}; }

    stage_tile(0, 0);
    stage_tile(1, 1);

    auto body = [&](int tt, short8* pa, short8* pbv, short8* npa, short8* nbv) {
        unsigned long long mwc = mw;
        mw = mrow[(tt + 1) & 31];
        stage_tile((tt + 2) & 3, (tt + 2) & 31);
        asm volatile("s_waitcnt vmcnt(10)" ::: "memory");
        __builtin_amdgcn_s_barrier();
        __builtin_amdgcn_sched_barrier(0);
        const unsigned short* L = &lds[tt & 3][0];
        short8 bkA[4], bkB[4];
        #pragma unroll
        for (int c = 0; c < 4; ++c) bkA[c] = *(const short8*)(L + c * 512 + lane * 8);
        #pragma unroll
        for (int c = 0; c < 4; ++c) bkB[c] = *(const short8*)(L + 2048 + c * 512 + lane * 8);
        #pragma unroll
        for (int z = 0; z < 8; ++z) nbv[z] = *(const short8*)(L + 4096 + z * 512 + lane * 8);
        f32x4 sA[4], sB[4];
        __builtin_amdgcn_s_setprio(1);
        #pragma unroll
        for (int c = 0; c < 4; ++c)
            sA[c] = __builtin_amdgcn_mfma_f32_16x16x32_bf16(bkA[c], aqA, (f32x4){0,0,0,0}, 0, 0, 0);
        #pragma unroll
        for (int c = 0; c < 4; ++c)
            sB[c] = __builtin_amdgcn_mfma_f32_16x16x32_bf16(bkB[c], aqB, (f32x4){0,0,0,0}, 0, 0, 0);
        #pragma unroll
        for (int m = 0; m < 4; ++m) {
            oA[m] = __builtin_amdgcn_mfma_f32_16x16x32_bf16(pa[0], pbv[m], oA[m], 0, 0, 0);
            oB[m] = __builtin_amdgcn_mfma_f32_16x16x32_bf16(pa[2], pbv[m], oB[m], 0, 0, 0);
        }
        #pragma unroll
        for (int m = 0; m < 4; ++m) {
            oA[m] = __builtin_amdgcn_mfma_f32_16x16x32_bf16(pa[1], pbv[4 + m], oA[m], 0, 0, 0);
            oB[m] = __builtin_amdgcn_mfma_f32_16x16x32_bf16(pa[3], pbv[4 + m], oB[m], 0, 0, 0);
        }
        __builtin_amdgcn_s_setprio(0);
        unsigned long long mwl = mwc >> (4 * lg);
        unsigned mlo = (unsigned)mwl, mhi = (unsigned)(mwl >> 32);
        float pA[4][4], pB[4][4];
        #pragma unroll
        for (int c = 0; c < 4; ++c) {
            unsigned wv = (c < 2) ? mlo : mhi;
            int sh = (c & 1) * 16;
            #pragma unroll
            for (int r = 0; r < 4; ++r) {
                unsigned keep = (wv >> (sh + r)) & 1u;
                float eA = expv(sA[c][r]);
                float eB = expv(sB[c][r]);
                pA[c][r] = keep ? eA : 0.f;
                pB[c][r] = keep ? eB : 0.f;
            }
        }
        union { short8 v; unsigned u[4]; } a0, a1, b0, b1;
        a0.u[0] = cvtpk(pA[0][0], pA[0][1]); a0.u[1] = cvtpk(pA[0][2], pA[0][3]);
        a0.u[2] = cvtpk(pA[1][0], pA[1][1]); a0.u[3] = cvtpk(pA[1][2], pA[1][3]);
        a1.u[0] = cvtpk(pA[2][0], pA[2][1]); a1.u[1] = cvtpk(pA[2][2], pA[2][3]);
        a1.u[2] = cvtpk(pA[3][0], pA[3][1]); a1.u[3] = cvtpk(pA[3][2], pA[3][3]);
        b0.u[0] = cvtpk(pB[0][0], pB[0][1]); b0.u[1] = cvtpk(pB[0][2], pB[0][3]);
        b0.u[2] = cvtpk(pB[1][0], pB[1][1]); b0.u[3] = cvtpk(pB[1][2], pB[1][3]);
        b1.u[0] = cvtpk(pB[2][0], pB[2][1]); b1.u[1] = cvtpk(pB[2][2], pB[2][3]);
        b1.u[2] = cvtpk(pB[3][0], pB[3][1]); b1.u[3] = cvtpk(pB[3][2], pB[3][3]);
        sumA = __builtin_amdgcn_mfma_f32_16x16x32_bf16(a0.v, one8, sumA, 0, 0, 0);
        sumA = __builtin_amdgcn_mfma_f32_16x16x32_bf16(a1.v, one8, sumA, 0, 0, 0);
        sumB = __builtin_amdgcn_mfma_f32_16x16x32_bf16(b0.v, one8, sumB, 0, 0, 0);
        sumB = __builtin_amdgcn_mfma_f32_16x16x32_bf16(b1.v, one8, sumB, 0, 0, 0);
        npa[0] = a0.v; npa[1] = a1.v; npa[2] = b0.v; npa[3] = b1.v;
    };

    for (int tp = 0; tp < 16; ++tp) {
        body(2 * tp,     paE, bvE, paO, bvO);
        body(2 * tp + 1, paO, bvO, paE, bvE);
    }
    #pragma unroll
    for (int m = 0; m < 4; ++m) {
        oA[m] = __builtin_amdgcn_mfma_f32_16x16x32_bf16(paE[0], bvE[m], oA[m], 0, 0, 0);
        oB[m] = __builtin_amdgcn_mfma_f32_16x16x32_bf16(paE[2], bvE[m], oB[m], 0, 0, 0);
    }
    #pragma unroll
    for (int m = 0; m < 4; ++m) {
        oA[m] = __builtin_amdgcn_mfma_f32_16x16x32_bf16(paE[1], bvE[4 + m], oA[m], 0, 0, 0);
        oB[m] = __builtin_amdgcn_mfma_f32_16x16x32_bf16(paE[3], bvE[4 + m], oB[m], 0, 0, 0);
    }
    // drain wrap-staged DMA so it can't land after LDS reuse / block exit
    asm volatile("s_waitcnt vmcnt(0)" ::: "memory");
    float iA[4], iB[4];
    #pragma unroll
    for (int r = 0; r < 4; ++r) {
        iA[r] = 1.f / sumA[r];
        iB[r] = 1.f / sumB[r];
    }
    int l31 = lane & 31;
    float t1 = lq1[l31] * lk1[l31];
    float t2 = lq2[l31] * lk2[l31];
    #pragma unroll
    for (int o = 1; o < 32; o <<= 1) { t1 += __shfl_xor(t1, o, 64); t2 += __shfl_xor(t2, o, 64); }
    float lam = __expf(t1) - __expf(t2) + LAMB_INIT;
    float dv[4][4];
    float sq[4] = {0.f, 0.f, 0.f, 0.f};
    #pragma unroll
    for (int m = 0; m < 4; ++m)
        #pragma unroll
        for (int r = 0; r < 4; ++r) {
            float v = oA[m][r] * iA[r] - lam * (oB[m][r] * iB[r]);
            dv[m][r] = v;
            sq[r] += v * v;
        }
    #pragma unroll
    for (int r = 0; r < 4; ++r) {
        #pragma unroll
        for (int o = 1; o < 16; o <<= 1) sq[r] += __shfl_xor(sq[r], o, 64);
        sq[r] = (1.f - LAMB_INIT) / (sqrtf(sq[r] * (1.f / 64.f)) + REPS);
    }
    float gm[4];
    #pragma unroll
    for (int m = 0; m < 4; ++m) gm[m] = gamma[16 * m + lr];
    unsigned short* Abp = Ab + ((size_t)(b * SEQL + q0 + 4 * lg)) * 512 + h * 64 + lr;
    #pragma unroll
    for (int m = 0; m < 4; ++m)
        #pragma unroll
        for (int r = 0; r < 4; ++r)
            Abp[(size_t)r * 512 + 16 * m] = f2bf(dv[m][r] * sq[r] * gm[m]);
}

// ---- proj unit: rows r0..r0+15 x one 16-col panel, full K=512 ----------------
static __device__ __forceinline__ void proj_unit(
        const unsigned short* __restrict__ Ab, const unsigned short* __restrict__ WfO,
        float* __restrict__ out, int r0, int ct, int lane, int lr, int lg) {
    f32x4 acc = (f32x4){0.f, 0.f, 0.f, 0.f};
    #pragma unroll
    for (int kk = 0; kk < 16; ++kk) {
        short8 af = *(const short8*)(Ab + (size_t)(r0 + lr) * 512 + kk * 32 + lg * 8);
        short8 bf = *(const short8*)(WfO + (size_t)(ct * 16 + kk) * 512 + lane * 8);
        acc = __builtin_amdgcn_mfma_f32_16x16x32_bf16(bf, af, acc, 0, 0, 0);
    }
    float4 st = { acc[0], acc[1], acc[2], acc[3] };
    *(float4*)(out + (size_t)(r0 + lr) * 128 + ct * 16 + 4 * lg) = st;
}

// ============================================================================
// 3-kernel pipeline (r14 best-known, graph-capture safe)
// ============================================================================
__global__ __launch_bounds__(256) void qkv_mask_kernel(
        const float* __restrict__ x, const float* __restrict__ Wq,
        const float* __restrict__ Wkv, const float* __restrict__ Wout,
        const unsigned char* __restrict__ mb, const int* __restrict__ mi,
        unsigned long long* __restrict__ bits,
        unsigned short* __restrict__ Q, unsigned short* __restrict__ Kf,
        unsigned short* __restrict__ Vf, unsigned short* __restrict__ WfO) {
    __shared__ unsigned short wlds[8192];
    __shared__ int cnt[256];
    int t = threadIdx.x, w = t >> 6, lane = t & 63, lr = lane & 15, lg = lane >> 4;
    {
        int c = 0;
        #pragma unroll
        for (int i = 0; i < 16; ++i) c += (mb[t * 16 + i] != 0);
        cnt[t] = c;
    }
    __syncthreads();
    for (int s = 128; s > 0; s >>= 1) { if (t < s) cnt[t] += cnt[t + s]; __syncthreads(); }
    int f = cnt[0] > 2048;
    for (int u = 0; u < 3; ++u) {
        int unit = blockIdx.x * 3 + u;
        int swzA = (unit & 7) * 192 + (unit >> 3);   // XCD-aware, bijective 0..1535
        __syncthreads();                  // prior unit's wlds reads done
        qkv_unit(x, Wq, Wkv, Q, Kf, Vf, wlds, swzA >> 6, swzA & 63, t, w, lane, lr, lg);
    }
    for (int wd = blockIdx.x * 4 + w; wd < 131072; wd += 2048) {
        int e = wd * 64 + lane;
        int v = f ? (int)mb[e] : mi[e];
        unsigned long long bl = __ballot(v != 0);
        if (lane == 0) bits[wd] = bl;
    }
    int g2 = blockIdx.x * 256 + t;
    if (g2 < 16384) {
        int cc = g2 & 127, k0 = (g2 >> 7) * 4;
        float v0 = Wout[(size_t)k0 * 128 + cc];
        float v1 = Wout[(size_t)(k0 + 1) * 128 + cc];
        float v2 = Wout[(size_t)(k0 + 2) * 128 + cc];
        float v3 = Wout[(size_t)(k0 + 3) * 128 + cc];
        int cp = cc >> 4, clr = cc & 15, kk = k0 >> 5, klg = (k0 >> 3) & 3, j0 = k0 & 7;
        uint2 pk;
        pk.x = cvtpk(v0, v1); pk.y = cvtpk(v2, v3);
        *(uint2*)(WfO + (size_t)(cp * 16 + kk) * 512 + klg * 128 + clr * 8 + j0) = pk;
    }
}

__global__ __launch_bounds__(256, 2) void attn_kernel(
        const unsigned short* __restrict__ Q, const unsigned short* __restrict__ Kf,
        const unsigned short* __restrict__ Vf, const unsigned long long* __restrict__ bits,
        const float* __restrict__ lq1, const float* __restrict__ lk1,
        const float* __restrict__ lq2, const float* __restrict__ lk2,
        const float* __restrict__ gamma, unsigned short* __restrict__ Ab) {
    __shared__ unsigned short lds[4][8192];
    int t = threadIdx.x, w = t >> 6, lane = t & 63, lr = lane & 15, lg = lane >> 4;
    attn_body(Q, Kf, Vf, bits, lq1, lk1, lq2, lk2, gamma, Ab,
              lds, blockIdx.y * 32 + blockIdx.x, w, lane, lr, lg);
}

__global__ __launch_bounds__(256) void proj_mfma_kernel(
        const unsigned short* __restrict__ Ab, const unsigned short* __restrict__ WfO,
        float* __restrict__ out) {
    int t = threadIdx.x, w = t >> 6, lane = t & 63, lr = lane & 15, lg = lane >> 4;
    proj_unit(Ab, WfO, out, (blockIdx.x >> 1) * 16, (blockIdx.x & 1) * 4 + w,
              lane, lr, lg);
}

extern "C" void kernel_launch(void* const* d_in, const int* in_sizes, int n_in,
                              void* d_out, int out_size, void* d_ws, size_t ws_size,
                              hipStream_t stream) {
    const float* x    = (const float*)d_in[0];
    const unsigned char* mb = (const unsigned char*)d_in[1];
    const int* mi     = (const int*)d_in[1];
    const float* Wq   = (const float*)d_in[2];
    const float* Wkv  = (const float*)d_in[3];
    const float* Wout = (const float*)d_in[4];
    const float* lq1  = (const float*)d_in[5];
    const float* lk1  = (const float*)d_in[6];
    const float* lq2  = (const float*)d_in[7];
    const float* lk2  = (const float*)d_in[8];
    const float* gam  = (const float*)d_in[9];
    float* out = (float*)d_out;

    char* wsb = (char*)d_ws;
    unsigned long long* bits = (unsigned long long*)(wsb + 4096);       // 1 MB
    unsigned short* Q        = (unsigned short*)(wsb + 1052672);        // 4 MB
    unsigned short* Kf       = (unsigned short*)(wsb + 5246976);        // 4 MB
    unsigned short* Vf       = (unsigned short*)(wsb + 9441280);        // 4 MB
    unsigned short* WfO      = (unsigned short*)(wsb + 15077376);       // 128 KB
    unsigned short* Ab       = (unsigned short*)(wsb + 15208448);       // 4 MB

    qkv_mask_kernel<<<512, 256, 0, stream>>>(x, Wq, Wkv, Wout, mb, mi,
                                             bits, Q, Kf, Vf, WfO);
    attn_kernel<<<dim3(32, 16), 256, 0, stream>>>(Q, Kf, Vf, bits,
                                                  lq1, lk1, lq2, lk2, gam, Ab);
    proj_mfma_kernel<<<512, 256, 0, stream>>>(Ab, WfO, out);
}

// Round 18
// 82.061 us; speedup vs baseline: 1.0849x; 1.0849x over previous
//
#include <hip/hip_runtime.h>
#include <float.h>
#include <math.h>

typedef __attribute__((ext_vector_type(8))) short short8;
typedef __attribute__((ext_vector_type(4))) float f32x4;

constexpr int SEQL = 2048;
constexpr int NQH  = 16;   // 2*H query/key heads
constexpr int NVH  = 8;    // value heads
constexpr int DHD  = 32;
constexpr float LAMB_INIT = 0.4707130183436648f;   // 0.8 - 0.6*exp(-0.6)
constexpr float REPS      = 1e-8f;
constexpr float QW        = 0.25503492f;           // 32^-0.5 * log2(e) (scores in log2 domain)

static __device__ __forceinline__ unsigned short f2bf(float f) {
    union { float f; unsigned u; } a; a.f = f;
    unsigned u = a.u;
    u += 0x7fffu + ((u >> 16) & 1u);
    return (unsigned short)(u >> 16);
}

static __device__ __forceinline__ unsigned cvtpk(float lo, float hi) {
    unsigned r;
    asm("v_cvt_pk_bf16_f32 %0, %1, %2" : "=v"(r) : "v"(lo), "v"(hi));
    return r;
}

// guaranteed single-instruction 2^x
static __device__ __forceinline__ float expv(float x) {
    float r;
    asm("v_exp_f32 %0, %1" : "=v"(r) : "v"(x));
    return r;
}

static __device__ __forceinline__ void stage16(const unsigned short* g, unsigned short* l) {
    __builtin_amdgcn_global_load_lds(
        (const __attribute__((address_space(1))) unsigned int*)g,
        (__attribute__((address_space(3))) unsigned int*)l, 16, 0, 0);
}

// ------- QKV projection via MFMA + mask bit-pack + WfO prep ---------------------
// 768 blocks (32 row-groups of 128 rows x 24 col-panels): each block preps its
// 16KB weight panel ONCE and uses it for TWO 64-row strips — fixed costs
// (detect, panel prep, barriers) amortize 2x.  Q/K panels: swapped operands ->
// 8B uint2 stores; V panel unswapped likewise.
// Tail 1: grid-strided mask bit-pack (dtype self-detected).
// Tail 2 (blocks 0-63): Wout -> WfO fragment prep (consumed by proj).
__global__ __launch_bounds__(256) void qkv_mask_kernel(
        const float* __restrict__ x, const float* __restrict__ Wq,
        const float* __restrict__ Wkv, const float* __restrict__ Wout,
        const unsigned char* __restrict__ mb, const int* __restrict__ mi,
        unsigned long long* __restrict__ bits,
        unsigned short* __restrict__ Q, unsigned short* __restrict__ Kf,
        unsigned short* __restrict__ Vf, unsigned short* __restrict__ WfO) {
    __shared__ unsigned short wlds[8192];     // 16KB: this block's B-fragments
    __shared__ int cnt[256];
    int t = threadIdx.x, w = t >> 6, lane = t & 63, lr = lane & 15, lg = lane >> 4;
    // ---- mask dtype detection (all blocks agree)
    {
        int c = 0;
        #pragma unroll
        for (int i = 0; i < 16; ++i) c += (mb[t * 16 + i] != 0);
        cnt[t] = c;
    }
    __syncthreads();
    for (int s = 128; s > 0; s >>= 1) { if (t < s) cnt[t] += cnt[t + s]; __syncthreads(); }
    int f = cnt[0] > 2048;
    // ---- block's panel: by = col-panel (24), bx = 128-row group (32)
    int lid = blockIdx.x;
    int swz = (lid & 7) * 96 + (lid >> 3);    // XCD-aware, bijective (768 % 8 == 0)
    int by = swz >> 5, bx = swz & 31;
    // ---- weight panel prep: 2048 k-quads -> LDS fragment order
    {
        const float* wsrc; int wstride, c0; float wscale;
        if (by < 8)       { wsrc = Wq;  wstride = 512;  c0 = by * 64;          wscale = QW;  }
        else if (by < 16) { wsrc = Wkv; wstride = 1024; c0 = (by - 8) * 64;    wscale = 1.f; }
        else              { wsrc = Wkv; wstride = 1024; c0 = 512 + (by - 16) * 64; wscale = 1.f; }
        #pragma unroll
        for (int i = 0; i < 8; ++i) {
            int q = t + i * 256;               // 0..2047
            int kq = q >> 6, c = q & 63;
            int k0 = kq * 4;
            const float* p = wsrc + (size_t)k0 * wstride + c0 + c;
            float v0 = p[0] * wscale;
            float v1 = p[wstride] * wscale;
            float v2 = p[2 * wstride] * wscale;
            float v3 = p[3 * wstride] * wscale;
            int ct = c >> 4, clr = c & 15, kk = k0 >> 5, klg = (k0 >> 3) & 3, j0 = k0 & 7;
            uint2 pk;
            pk.x = cvtpk(v0, v1); pk.y = cvtpk(v2, v3);
            *(uint2*)(wlds + (size_t)(ct * 4 + kk) * 512 + klg * 128 + clr * 8 + j0) = pk;
        }
    }
    // ---- x A-fragments for BOTH strips (f32 -> bf16 in-register)
    int rbase = bx * 128 + w * 16;
    short8 ax[2][4];
    #pragma unroll
    for (int s = 0; s < 2; ++s)
        #pragma unroll
        for (int kk = 0; kk < 4; ++kk) {
            const float* xp = x + (size_t)(rbase + 64 * s + lr) * 128 + kk * 32 + lg * 8;
            float4 v0 = *(const float4*)xp;
            float4 v1 = *(const float4*)(xp + 4);
            union { short8 v; unsigned u[4]; } ua;
            ua.u[0] = cvtpk(v0.x, v0.y);
            ua.u[1] = cvtpk(v0.z, v0.w);
            ua.u[2] = cvtpk(v1.x, v1.y);
            ua.u[3] = cvtpk(v1.z, v1.w);
            ax[s][kk] = ua.v;
        }
    __syncthreads();                          // panel ready
    if (by < 16) {
        // swapped: D[i=4lg+r = col-in-16][j=lr = x-row] -> 8B stores
        #pragma unroll
        for (int s = 0; s < 2; ++s) {
            f32x4 acc[4];
            #pragma unroll
            for (int ct = 0; ct < 4; ++ct) acc[ct] = (f32x4){0.f, 0.f, 0.f, 0.f};
            #pragma unroll
            for (int ct = 0; ct < 4; ++ct)
                #pragma unroll
                for (int kk = 0; kk < 4; ++kk) {
                    short8 bw = *(const short8*)(wlds + (size_t)(ct * 4 + kk) * 512 + lane * 8);
                    acc[ct] = __builtin_amdgcn_mfma_f32_16x16x32_bf16(bw, ax[s][kk], acc[ct], 0, 0, 0);
                }
            int gr = rbase + 64 * s + lr;
            int l = gr & 2047, b = gr >> 11;
            if (by < 8) {                      // Q row-major (b,n,l,d)
                #pragma unroll
                for (int ct = 0; ct < 4; ++ct) {
                    int col = by * 64 + ct * 16 + 4 * lg;
                    int n = col >> 5, d = col & 31;
                    uint2 pk;
                    pk.x = cvtpk(acc[ct][0], acc[ct][1]);
                    pk.y = cvtpk(acc[ct][2], acc[ct][3]);
                    *(uint2*)(Q + (((size_t)(b * NQH + n)) * SEQL + l) * DHD + d) = pk;
                }
            } else {                           // Kf fragment order
                size_t lpart = (size_t)((l >> 6) * 4 + ((l >> 4) & 3)) * 512 + (l & 15) * 8;
                #pragma unroll
                for (int ct = 0; ct < 4; ++ct) {
                    int ck = by * 64 + ct * 16 + 4 * lg - 512;
                    int n = ck >> 5, dk = ck & 31;
                    uint2 pk;
                    pk.x = cvtpk(acc[ct][0], acc[ct][1]);
                    pk.y = cvtpk(acc[ct][2], acc[ct][3]);
                    *(uint2*)(Kf + ((size_t)(b * NQH + n)) * 65536 + lpart
                                 + (dk >> 3) * 128 + (dk & 7)) = pk;
                }
            }
        }
    } else {
        // unswapped: D[i=4lg+r = x-row][j=lr = col-in-16]
        #pragma unroll
        for (int s = 0; s < 2; ++s) {
            f32x4 acc[4];
            #pragma unroll
            for (int ct = 0; ct < 4; ++ct) acc[ct] = (f32x4){0.f, 0.f, 0.f, 0.f};
            #pragma unroll
            for (int ct = 0; ct < 4; ++ct)
                #pragma unroll
                for (int kk = 0; kk < 4; ++kk) {
                    short8 bw = *(const short8*)(wlds + (size_t)(ct * 4 + kk) * 512 + lane * 8);
                    acc[ct] = __builtin_amdgcn_mfma_f32_16x16x32_bf16(ax[s][kk], bw, acc[ct], 0, 0, 0);
                }
            int gr0 = rbase + 64 * s + 4 * lg;
            int b = gr0 >> 11, l0 = gr0 & 2047;
            size_t lpart = (size_t)((l0 >> 6) * 2 + ((l0 >> 5) & 1)) * 2048
                         + ((l0 >> 4) & 1) * 4 + ((l0 >> 2) & 3) * 128;   // + u(=r)
            #pragma unroll
            for (int ct = 0; ct < 4; ++ct) {
                int cv = by * 64 + 16 * ct + lr - 1024;
                int h = cv >> 6, d = cv & 63;
                uint2 pk;
                pk.x = cvtpk(acc[ct][0], acc[ct][1]);
                pk.y = cvtpk(acc[ct][2], acc[ct][3]);
                *(uint2*)(Vf + ((size_t)(b * NVH + h)) * 131072
                             + (size_t)(d >> 4) * 512 + (d & 15) * 8 + lpart) = pk;
            }
        }
    }
    // ---- tail 1: mask bit-pack (grid-strided, 768 blocks x 4 waves)
    int wd0 = blockIdx.x * 4 + w;
    for (int wd = wd0; wd < 131072; wd += 3072) {
        int e = wd * 64 + lane;
        int v = f ? (int)mb[e] : mi[e];
        unsigned long long bl = __ballot(v != 0);
        if (lane == 0) bits[wd] = bl;
    }
    // ---- tail 2: Wout -> WfO fragment prep (blocks 0-63; consumed by proj)
    int g2 = blockIdx.x * 256 + t;
    if (g2 < 16384) {
        int cc = g2 & 127, k0 = (g2 >> 7) * 4;
        float v0 = Wout[(size_t)k0 * 128 + cc];
        float v1 = Wout[(size_t)(k0 + 1) * 128 + cc];
        float v2 = Wout[(size_t)(k0 + 2) * 128 + cc];
        float v3 = Wout[(size_t)(k0 + 3) * 128 + cc];
        int cp = cc >> 4, clr = cc & 15, kk = k0 >> 5, klg = (k0 >> 3) & 3, j0 = k0 & 7;
        uint2 pk;
        pk.x = cvtpk(v0, v1); pk.y = cvtpk(v2, v3);
        *(uint2*)(WfO + (size_t)(cp * 16 + kk) * 512 + klg * 128 + clr * 8 + j0) = pk;
    }
}

// ---------------- fused flash attention, head-paired, LDS-pipelined -------------
// r5/r11/r12 schedule (best measured across 12+ structural variants).
// Denominator via MFMA-ones on the idle matrix pipe (sums land in (4lg+r) layout).
__global__ __launch_bounds__(256, 2) void attn_kernel(
        const unsigned short* __restrict__ Q, const unsigned short* __restrict__ Kf,
        const unsigned short* __restrict__ Vf, const unsigned long long* __restrict__ bits,
        const float* __restrict__ lq1, const float* __restrict__ lk1,
        const float* __restrict__ lq2, const float* __restrict__ lk2,
        const float* __restrict__ gamma, unsigned short* __restrict__ A) {
    __shared__ unsigned short lds[4][8192];   // [KA 4K][KB 4K][V 8K] elems per buf
    int tid = threadIdx.x;
    int w = tid >> 6, lane = tid & 63;
    int lr = lane & 15, lg = lane >> 4;
    int lid = blockIdx.y * 32 + blockIdx.x;
    int swz = (lid & 7) * 64 + (lid >> 3);    // XCD-aware
    int qtile = swz & 31, bh = swz >> 5;
    int b = bh >> 3, h = bh & 7;
    int q0 = qtile * 64 + w * 16;
    int bnA = b * NQH + 2 * h;

    short8 aqA = *(const short8*)(Q + (((size_t)bnA) * SEQL + q0 + lr) * DHD + lg * 8);
    short8 aqB = *(const short8*)(Q + (((size_t)(bnA + 1)) * SEQL + q0 + lr) * DHD + lg * 8);
    const unsigned short* KA = Kf + ((size_t)bnA) * 65536;
    const unsigned short* KB = KA + 65536;
    const unsigned short* VB = Vf + ((size_t)(b * NVH + h)) * 131072;
    const unsigned long long* mrow = bits + ((size_t)b * SEQL + q0 + lr) * 32;

    short8 one8;
    #pragma unroll
    for (int i = 0; i < 8; ++i) one8[i] = (short)0x3F80;   // bf16 1.0

    auto stage_tile = [&](int bf, int it) {
        #pragma unroll
        for (int j = 0; j < 4; ++j) {
            int c = 4 * w + j;
            const unsigned short* src =
                (c < 4) ? (KA + (size_t)it * 2048 + c * 512)
              : (c < 8) ? (KB + (size_t)it * 2048 + (c - 4) * 512)
                        : (VB + (size_t)it * 4096 + (c - 8) * 512);
            stage16(src + lane * 8, &lds[bf][c * 512]);
        }
    };

    f32x4 oA[4], oB[4], sumA, sumB;
    #pragma unroll
    for (int m = 0; m < 4; ++m) { oA[m] = (f32x4){0,0,0,0}; oB[m] = (f32x4){0,0,0,0}; }
    sumA = (f32x4){0,0,0,0}; sumB = (f32x4){0,0,0,0};
    unsigned long long mw = mrow[0];

    // even/odd pipeline register sets
    short8 paE[4], paO[4], bvE[8], bvO[8];
    #pragma unroll
    for (int i = 0; i < 4; ++i) { paE[i] = (short8){0,0,0,0,0,0,0,0}; paO[i] = (short8){0,0,0,0,0,0,0,0}; }
    #pragma unroll
    for (int i = 0; i < 8; ++i) { bvE[i] = (short8){0,0,0,0,0,0,0,0}; bvO[i] = (short8){0,0,0,0,0,0,0,0}; }

    stage_tile(0, 0);
    stage_tile(1, 1);

    auto body = [&](int t, short8* pa, short8* pbv, short8* npa, short8* nbv) {
        unsigned long long mwc = mw;
        mw = mrow[(t + 1) & 31];
        stage_tile((t + 2) & 3, (t + 2) & 31);
        asm volatile("s_waitcnt vmcnt(10)" ::: "memory");
        __builtin_amdgcn_s_barrier();
        __builtin_amdgcn_sched_barrier(0);
        const unsigned short* L = &lds[t & 3][0];
        short8 bkA[4], bkB[4];
        #pragma unroll
        for (int c = 0; c < 4; ++c) bkA[c] = *(const short8*)(L + c * 512 + lane * 8);
        #pragma unroll
        for (int c = 0; c < 4; ++c) bkB[c] = *(const short8*)(L + 2048 + c * 512 + lane * 8);
        #pragma unroll
        for (int z = 0; z < 8; ++z) nbv[z] = *(const short8*)(L + 4096 + z * 512 + lane * 8);
        f32x4 sA[4], sB[4];
        __builtin_amdgcn_s_setprio(1);
        #pragma unroll
        for (int c = 0; c < 4; ++c)
            sA[c] = __builtin_amdgcn_mfma_f32_16x16x32_bf16(bkA[c], aqA, (f32x4){0,0,0,0}, 0, 0, 0);
        #pragma unroll
        for (int c = 0; c < 4; ++c)
            sB[c] = __builtin_amdgcn_mfma_f32_16x16x32_bf16(bkB[c], aqB, (f32x4){0,0,0,0}, 0, 0, 0);
        // delayed PV for previous tile (registers only)
        #pragma unroll
        for (int m = 0; m < 4; ++m) {
            oA[m] = __builtin_amdgcn_mfma_f32_16x16x32_bf16(pa[0], pbv[m], oA[m], 0, 0, 0);
            oB[m] = __builtin_amdgcn_mfma_f32_16x16x32_bf16(pa[2], pbv[m], oB[m], 0, 0, 0);
        }
        #pragma unroll
        for (int m = 0; m < 4; ++m) {
            oA[m] = __builtin_amdgcn_mfma_f32_16x16x32_bf16(pa[1], pbv[4 + m], oA[m], 0, 0, 0);
            oB[m] = __builtin_amdgcn_mfma_f32_16x16x32_bf16(pa[3], pbv[4 + m], oB[m], 0, 0, 0);
        }
        __builtin_amdgcn_s_setprio(0);
        // masked exp2 (scores bounded; no max subtraction), lane-local
        unsigned long long mwl = mwc >> (4 * lg);
        unsigned mlo = (unsigned)mwl, mhi = (unsigned)(mwl >> 32);
        float pA[4][4], pB[4][4];
        #pragma unroll
        for (int c = 0; c < 4; ++c) {
            unsigned wv = (c < 2) ? mlo : mhi;
            int sh = (c & 1) * 16;
            #pragma unroll
            for (int r = 0; r < 4; ++r) {
                unsigned keep = (wv >> (sh + r)) & 1u;
                float eA = expv(sA[c][r]);
                float eB = expv(sB[c][r]);
                pA[c][r] = keep ? eA : 0.f;
                pB[c][r] = keep ? eB : 0.f;
            }
        }
        union { short8 v; unsigned u[4]; } a0, a1, b0, b1;
        a0.u[0] = cvtpk(pA[0][0], pA[0][1]); a0.u[1] = cvtpk(pA[0][2], pA[0][3]);
        a0.u[2] = cvtpk(pA[1][0], pA[1][1]); a0.u[3] = cvtpk(pA[1][2], pA[1][3]);
        a1.u[0] = cvtpk(pA[2][0], pA[2][1]); a1.u[1] = cvtpk(pA[2][2], pA[2][3]);
        a1.u[2] = cvtpk(pA[3][0], pA[3][1]); a1.u[3] = cvtpk(pA[3][2], pA[3][3]);
        b0.u[0] = cvtpk(pB[0][0], pB[0][1]); b0.u[1] = cvtpk(pB[0][2], pB[0][3]);
        b0.u[2] = cvtpk(pB[1][0], pB[1][1]); b0.u[3] = cvtpk(pB[1][2], pB[1][3]);
        b1.u[0] = cvtpk(pB[2][0], pB[2][1]); b1.u[1] = cvtpk(pB[2][2], pB[2][3]);
        b1.u[2] = cvtpk(pB[3][0], pB[3][1]); b1.u[3] = cvtpk(pB[3][2], pB[3][3]);
        // denominator partial sums on the matrix pipe: sum += P_tile @ ones
        sumA = __builtin_amdgcn_mfma_f32_16x16x32_bf16(a0.v, one8, sumA, 0, 0, 0);
        sumA = __builtin_amdgcn_mfma_f32_16x16x32_bf16(a1.v, one8, sumA, 0, 0, 0);
        sumB = __builtin_amdgcn_mfma_f32_16x16x32_bf16(b0.v, one8, sumB, 0, 0, 0);
        sumB = __builtin_amdgcn_mfma_f32_16x16x32_bf16(b1.v, one8, sumB, 0, 0, 0);
        npa[0] = a0.v; npa[1] = a1.v; npa[2] = b0.v; npa[3] = b1.v;
    };

    for (int tp = 0; tp < 16; ++tp) {
        body(2 * tp,     paE, bvE, paO, bvO);
        body(2 * tp + 1, paO, bvO, paE, bvE);
    }
    // final PV for tile 31 (lives in E set)
    #pragma unroll
    for (int m = 0; m < 4; ++m) {
        oA[m] = __builtin_amdgcn_mfma_f32_16x16x32_bf16(paE[0], bvE[m], oA[m], 0, 0, 0);
        oB[m] = __builtin_amdgcn_mfma_f32_16x16x32_bf16(paE[2], bvE[m], oB[m], 0, 0, 0);
    }
    #pragma unroll
    for (int m = 0; m < 4; ++m) {
        oA[m] = __builtin_amdgcn_mfma_f32_16x16x32_bf16(paE[1], bvE[4 + m], oA[m], 0, 0, 0);
        oB[m] = __builtin_amdgcn_mfma_f32_16x16x32_bf16(paE[3], bvE[4 + m], oB[m], 0, 0, 0);
    }
    // drain wrap-staged DMA so it can't land in a successor block's LDS
    asm volatile("s_waitcnt vmcnt(0)" ::: "memory");
    // ---- epilogue: sums already in (4lg+r) layout — no shuffles needed
    float iA[4], iB[4];
    #pragma unroll
    for (int r = 0; r < 4; ++r) {
        iA[r] = 1.f / sumA[r];
        iB[r] = 1.f / sumB[r];
    }
    int l31 = lane & 31;
    float t1 = lq1[l31] * lk1[l31];
    float t2 = lq2[l31] * lk2[l31];
    #pragma unroll
    for (int o = 1; o < 32; o <<= 1) { t1 += __shfl_xor(t1, o, 64); t2 += __shfl_xor(t2, o, 64); }
    float lam = __expf(t1) - __expf(t2) + LAMB_INIT;
    float dv[4][4];
    float sq[4] = {0.f, 0.f, 0.f, 0.f};
    #pragma unroll
    for (int m = 0; m < 4; ++m)
        #pragma unroll
        for (int r = 0; r < 4; ++r) {
            float v = oA[m][r] * iA[r] - lam * (oB[m][r] * iB[r]);
            dv[m][r] = v;
            sq[r] += v * v;
        }
    #pragma unroll
    for (int r = 0; r < 4; ++r) {
        #pragma unroll
        for (int o = 1; o < 16; o <<= 1) sq[r] += __shfl_xor(sq[r], o, 64);
        sq[r] = (1.f - LAMB_INIT) / (sqrtf(sq[r] * (1.f / 64.f)) + REPS);
    }
    float gm[4];
    #pragma unroll
    for (int m = 0; m < 4; ++m) gm[m] = gamma[16 * m + lr];
    unsigned short* Ab = A + ((size_t)(b * SEQL + q0 + 4 * lg)) * 512 + h * 64 + lr;
    #pragma unroll
    for (int m = 0; m < 4; ++m)
        #pragma unroll
        for (int r = 0; r < 4; ++r)
            Ab[(size_t)r * 512 + 16 * m] = f2bf(dv[m][r] * sq[r] * gm[m]);
}

// ---------------- output projection via MFMA: one ct-column per wave ------------
// 512 blocks (256 row-tiles x 2 ct-halves) x 4 waves; wave = 1 out-col-panel,
// full K=512 — no LDS, no syncthreads.  Swapped operands -> float4 stores.
__global__ __launch_bounds__(256) void proj_mfma_kernel(
        const unsigned short* __restrict__ Ab, const unsigned short* __restrict__ WfO,
        float* __restrict__ out) {
    int t = threadIdx.x, w = t >> 6, lane = t & 63, lr = lane & 15, lg = lane >> 4;
    int bid = blockIdx.x;
    int r0 = (bid >> 1) * 16;
    int ct = (bid & 1) * 4 + w;
    f32x4 acc = (f32x4){0.f, 0.f, 0.f, 0.f};
    #pragma unroll
    for (int kk = 0; kk < 16; ++kk) {
        short8 af = *(const short8*)(Ab + (size_t)(r0 + lr) * 512 + kk * 32 + lg * 8);
        short8 bf = *(const short8*)(WfO + (size_t)(ct * 16 + kk) * 512 + lane * 8);
        acc = __builtin_amdgcn_mfma_f32_16x16x32_bf16(bf, af, acc, 0, 0, 0);
    }
    float4 st = { acc[0], acc[1], acc[2], acc[3] };
    *(float4*)(out + (size_t)(r0 + lr) * 128 + ct * 16 + 4 * lg) = st;
}

extern "C" void kernel_launch(void* const* d_in, const int* in_sizes, int n_in,
                              void* d_out, int out_size, void* d_ws, size_t ws_size,
                              hipStream_t stream) {
    const float* x    = (const float*)d_in[0];
    const void*  mask = d_in[1];
    const float* Wq   = (const float*)d_in[2];
    const float* Wkv  = (const float*)d_in[3];
    const float* Wout = (const float*)d_in[4];
    const float* lq1  = (const float*)d_in[5];
    const float* lk1  = (const float*)d_in[6];
    const float* lq2  = (const float*)d_in[7];
    const float* lk2  = (const float*)d_in[8];
    const float* gam  = (const float*)d_in[9];
    float* out = (float*)d_out;

    char* wsb = (char*)d_ws;
    unsigned long long* bits = (unsigned long long*)(wsb + 4096);       // 1 MB
    unsigned short* Q        = (unsigned short*)(wsb + 1052672);        // 4 MB
    unsigned short* Kf       = (unsigned short*)(wsb + 5246976);        // 4 MB
    unsigned short* Vf       = (unsigned short*)(wsb + 9441280);        // 4 MB
    unsigned short* WfO      = (unsigned short*)(wsb + 15077376);       // 128 KB
    unsigned short* Ab       = (unsigned short*)(wsb + 15208448);       // 4 MB

    qkv_mask_kernel<<<768, 256, 0, stream>>>(x, Wq, Wkv, Wout,
                                             (const unsigned char*)mask,
                                             (const int*)mask, bits, Q, Kf, Vf, WfO);
    attn_kernel<<<dim3(32, 16), 256, 0, stream>>>(Q, Kf, Vf, bits,
                                                  lq1, lk1, lq2, lk2, gam, Ab);
    proj_mfma_kernel<<<512, 256, 0, stream>>>(Ab, WfO, out);
}